// Round 13
// baseline (150.839 us; speedup 1.0000x reference)
//
#include <hip/hip_runtime.h>
#include <math.h>

#define Bb 8
#define Nn 64
#define Ff 32
#define Tt 4
#define OUTn 128
#define NPAIR 2016   // 64*63/2 lower-triangle pairs (i>j)

__device__ __forceinline__ float sigmoidf_(float x){ return 1.0f/(1.0f+expf(-x)); }

__device__ __forceinline__ void p2ij(int p, int& i, int& j){
  int ii = (int)((1.0f + sqrtf(1.0f + 8.0f*(float)p)) * 0.5f);
  while (ii*(ii-1)/2 > p) --ii;
  while ((ii+1)*ii/2 <= p) ++ii;
  i = ii; j = p - ii*(ii-1)/2;
}

// sequential-order fp32 dot (bit-identical to the validated round-0 ordering;
// the floor(sigmoid) gate is discontinuous -> this order must not change)
__device__ __forceinline__ float dot32(const float4* __restrict__ u, const float* __restrict__ v){
  const float4* v4 = (const float4*)v;
  float d = 0.f;
#pragma unroll
  for (int q=0;q<8;++q){
    float4 a=u[q], b=v4[q];
    d = fmaf(a.x,b.x,d); d = fmaf(a.y,b.y,d);
    d = fmaf(a.z,b.z,d); d = fmaf(a.w,b.w,d);
  }
  return d;
}

// ---- precompute wzxb/wcxb for lower-tri pairs + fused t=0 update ----
// t=0: M=0 -> m_other=0, gated_sum=0, r_msg=0
//   => m_full0 = sigmoid(wzxb) * tanh(wcxb)   (bit-exact)
__global__ __launch_bounds__(64) void precompute_pair(
    const float* __restrict__ x,
    const float* __restrict__ w_z,
    const float* __restrict__ w_c,
    const float* __restrict__ b_z,
    const float* __restrict__ b_c,
    float* __restrict__ wzxb,
    float* __restrict__ wcxb,
    float* __restrict__ mf0) {
  int p = blockIdx.x;
  int i, j; p2ij(p, i, j);
  int l = threadIdx.x, f = l & 31, h = l >> 5;

  __shared__ __align__(16) float xL[Bb][Ff];
  __shared__ __align__(16) float valL[2][Bb][Ff];
  for (int q = l; q < Bb*Ff; q += 64) {
    int b = q >> 5, g = q & 31;
    xL[b][g] = x[(b*Nn + i)*Ff + g];
  }
  __syncthreads();

  const float* W = h ? w_c : w_z;
  const float4* w4 = (const float4*)&W[(((size_t)i*Nn + j)*Ff + f)*Ff];
  float4 w[8];
#pragma unroll
  for (int q=0;q<8;++q) w[q]=w4[q];
  float bias = h ? b_c[f] : b_z[f];
  float* dst = h ? wcxb : wzxb;
#pragma unroll
  for (int b=0;b<Bb;++b){
    float v = dot32(w, xL[b]) + bias;
    dst[((size_t)(b*Nn + i)*Nn + j)*Ff + f] = v;
    valL[h][b][f] = v;
  }
  __syncthreads();
  if (h == 0) {
#pragma unroll
    for (int b=0;b<Bb;++b){
      mf0[((size_t)(b*Nn + i)*Nn + j)*Ff + f] =
          sigmoidf_(valL[0][b][f]) * tanhf(valL[1][b][f]);
    }
  }
}

// ---- one MP iteration (t>=1); block = (b, i, j-half), 256 threads ----
// (the 141-us champion structure; only change: the two intra-half-wave
//  LDS RAW barriers in the rare-fire path are removed - lockstep-safe)
__global__ __launch_bounds__(256) void edge_update(
    const float* __restrict__ A,
    const float* __restrict__ u_z,
    const float* __restrict__ u_c,
    const float* __restrict__ wzxb,
    const float* __restrict__ wcxb,
    const float* __restrict__ mfp,
    float* __restrict__ mfn) {
  int b  = blockIdx.x;   // 8
  int i  = blockIdx.y;   // 64
  int jh = blockIdx.z;   // 2
  int tid = threadIdx.x;

  __shared__ __align__(16) float Mc [Nn][Ff];
  __shared__ __align__(16) float moL[32][Ff];
  __shared__ __align__(16) float gsL[32][Ff];
  __shared__ __align__(16) float rmL[32][Ff];
  __shared__ float aggL[Ff];
  __shared__ float normL[Nn];
  __shared__ int nbrL[Nn];
  __shared__ int jlistL[32], jslotL[32];
  __shared__ int nnL, jcL;

  if (tid < 64) {
    float a = A[(b*Nn + i)*Nn + tid];
    bool e = (a != 0.0f);
    unsigned long long m = __ballot(e);
    if (e) nbrL[__popcll(m & ((1ull << tid) - 1ull))] = tid;
    bool ej = e && (tid < i);
    unsigned long long mj = __ballot(ej);
    if (ej) {
      int r = __popcll(mj & ((1ull << tid) - 1ull));
      if ((r & 1) == jh) {
        int jl = r >> 1;
        jlistL[jl] = tid;
        jslotL[jl] = __popcll(m & ((1ull << tid) - 1ull));
      }
    }
    if (tid == 0) {
      nnL = __popcll(m);
      jcL = (__popcll(mj) + 1 - jh) >> 1;
    }
  }
  __syncthreads();
  int nn = nnL, jc = jcL;
  if (jc == 0) return;
  int P = jc * Ff;

  // prefetch round-0 operands; latency hides under Mc staging + agg/norm
  bool act0 = tid < P;
  int jl0 = act0 ? (tid >> 5) : 0;
  int f0 = tid & 31;
  int j0 = jlistL[jl0];
  int jslot0 = jslotL[jl0];
  size_t eoff0 = ((size_t)(b*Nn + i)*Nn + j0)*Ff + f0;
  float4 u0[8];
  float wb0 = -1.0e30f;
  if (act0) {
    const float4* u4 = (const float4*)&u_z[(((size_t)i*Nn + j0)*Ff + f0)*Ff];
#pragma unroll
    for (int q=0;q<8;++q) u0[q] = u4[q];
    wb0 = wzxb[eoff0];
  } else {
#pragma unroll
    for (int q=0;q<8;++q) u0[q] = make_float4(0.f,0.f,0.f,0.f);
  }

  // stage compact M rows
  for (int q = tid; q < nn*Ff; q += 256) {
    int s = q >> 5, f = q & 31;
    int k = nbrL[s];
    int hi = i > k ? i : k, lo = i > k ? k : i;
    Mc[s][f] = mfp[((size_t)(b*Nn + hi)*Nn + lo)*Ff + f];
  }
  __syncthreads();
  // agg (ascending k, matches reference) + zero-padded row norms (screen)
  if (tid < Ff) {
    float sAcc = 0.f;
    for (int s = 0; s < nn; ++s) sAcc += Mc[s][tid];
    aggL[tid] = sAcc;
  }
  if (tid >= 64 && tid < 128) {
    int s = tid - 64;
    float nv = 0.f;
    if (s < nn) {
      float ss = 0.f;
      for (int g = 0; g < Ff; ++g) { float v = Mc[s][g]; ss = fmaf(v,v,ss); }
      nv = sqrtf(ss);
    }
    normL[s] = nv;   // 0 for padded k >= nn
  }
  __syncthreads();
  for (int q = tid; q < P; q += 256) {
    int jl = q >> 5, f = q & 31;
    moL[jl][f] = aggL[f] - Mc[jslotL[jl]][f];
  }
  __syncthreads();

  int NR = (P + 255) >> 8;
  int nn8 = (nn + 7) & ~7;
  for (int r = 0; r < NR; ++r) {
    int p = tid + (r << 8);
    bool act = p < P;
    int jl, f, j, jslot; size_t eoff;
    float4 u[8]; float wb;
    if (r == 0) {
      jl = jl0; f = f0; j = j0; jslot = jslot0; eoff = eoff0; wb = wb0;
#pragma unroll
      for (int q=0;q<8;++q) u[q] = u0[q];
    } else {
      jl = act ? (p >> 5) : 0;
      f = p & 31;
      j = jlistL[jl]; jslot = jslotL[jl];
      eoff = ((size_t)(b*Nn + i)*Nn + j)*Ff + f;
      wb = -1.0e30f;
      if (act) {
        const float4* u4 = (const float4*)&u_z[(((size_t)i*Nn + j)*Ff + f)*Ff];
#pragma unroll
        for (int q=0;q<8;++q) u[q] = u4[q];
        wb = wzxb[eoff];
      } else {
#pragma unroll
        for (int q=0;q<8;++q) u[q] = make_float4(0.f,0.f,0.f,0.f);
      }
    }

    float un = 0.f;
#pragma unroll
    for (int q=0;q<8;++q){
      float4 a=u[q];
      un = fmaf(a.x,a.x,un); un = fmaf(a.y,a.y,un);
      un = fmaf(a.z,a.z,un); un = fmaf(a.w,a.w,un);
    }
    un = sqrtf(un);

    float z = 0.f;
    if (act) z = sigmoidf_(wb + dot32(u, moL[jl]));

    // Cauchy-Schwarz screen, pipelined mask loop (per-(f,k) ballot -
    // the tightest validated screen; conservative, grouping-independent)
    unsigned long long kmask = 0ull;
#pragma unroll 8
    for (int k = 0; k < nn8; ++k) {
      unsigned long long bb = __ballot(wb + un * normL[k] >= 15.5f);
      if (bb) kmask |= 1ull << k;
    }

    float gs = 0.f;
    if (kmask) {
#pragma unroll 2
      for (int k = 0; k < nn; ++k) {
        if ((kmask >> k) & 1) {
          float v = wb + dot32(u, Mc[k]);
          if (act && k != jslot && v >= 16.0f &&
              (v > 17.5f || sigmoidf_(v) >= 1.0f)) gs += Mc[k][f];
        }
      }
    }
    if (act) gsL[jl][f] = gs;

    // rare fire path: gsL/rmL RAW is intra-half-wave (lockstep) -> no barriers
    unsigned long long bal = __ballot(act && gs != 0.0f);
    bool rowfire = ((bal >> (tid & 32)) & 0xFFFFFFFFull) != 0ull;

    float4 uc[8]; float d2 = 0.f;
    if (act && rowfire) {
      const float4* uc4 = (const float4*)&u_c[(((size_t)i*Nn + j)*Ff + f)*Ff];
#pragma unroll
      for (int q=0;q<8;++q) uc[q]=uc4[q];
      rmL[jl][f] = dot32(uc, gsL[jl]);
    }
    if (act && rowfire) d2 = dot32(uc, rmL[jl]);

    if (act) {
      float cur = tanhf(wcxb[eoff] + d2);
      mfn[eoff] = (1.0f - z)*moL[jl][f] + z*cur;
    }
    __syncthreads();   // protect moL/gsL/rmL reuse across r-rounds
  }
}

// ---- msg_sum gather + enc = relu(u_node.x + u_msg.msg_sum) ----
__global__ __launch_bounds__(64) void finalize_enc(
    const float* __restrict__ x,
    const float* __restrict__ A,
    const float* __restrict__ mf,
    const float* __restrict__ u_node,
    const float* __restrict__ u_msg,
    float* __restrict__ enc) {
  int bi = blockIdx.x;
  int b = bi >> 6, i = bi & 63;
  int l = threadIdx.x, f = l & 31, h = l >> 5;

  float a = A[(b*Nn + i)*Nn + l];
  unsigned long long mask = __ballot(a != 0.0f);
  float acc = 0.f;
  unsigned long long mm = mask;
  int idx = 0;
  while (mm) {
    int k = __builtin_ctzll(mm);
    mm &= mm - 1;
    if ((idx & 1) == h) {
      int hi = i > k ? i : k, lo = i > k ? k : i;
      acc += mf[((size_t)(b*Nn + hi)*Nn + lo)*Ff + f];
    }
    idx++;
  }
  float accO = __shfl(acc, l ^ 32);
  acc += accO;

  __shared__ __align__(16) float vecL[2][Ff];
  if (l < 32) { vecL[0][l] = x[(b*Nn + i)*Ff + l]; vecL[1][l] = acc; }
  __syncthreads();
  const float* Urow = (h == 0) ? &u_node[((size_t)i*Ff + f)*Ff]
                               : &u_msg [((size_t)i*Ff + f)*Ff];
  const float4* w4 = (const float4*)Urow;
  float4 w[8];
#pragma unroll
  for (int q=0;q<8;++q) w[q]=w4[q];
  float d = dot32(w, vecL[h]);
  float dO = __shfl(d, l ^ 32);
  if (l < 32) enc[(b*Nn + i)*Ff + f] = fmaxf(d + dO, 0.0f);
}

// ---- output linear + sigmoid: one wave per (b, o) output element ----
__global__ __launch_bounds__(64) void linear_out(
    const float* __restrict__ enc,
    const float* __restrict__ lin_w,
    const float* __restrict__ lin_b,
    float* __restrict__ out) {
  int b = blockIdx.x >> 7;        // 8
  int o = blockIdx.x & 127;       // 128
  int l = threadIdx.x;            // 64
  const float4* w4 = (const float4*)&lin_w[(size_t)o*(Nn*Ff)];
  const float4* e4 = (const float4*)&enc[(size_t)b*(Nn*Ff)];
  float acc = 0.f;
#pragma unroll
  for (int q = 0; q < 8; ++q) {
    float4 w = w4[q*64 + l], e = e4[q*64 + l];
    acc = fmaf(w.x,e.x,acc); acc = fmaf(w.y,e.y,acc);
    acc = fmaf(w.z,e.z,acc); acc = fmaf(w.w,e.w,acc);
  }
  acc += __shfl_xor(acc, 1);  acc += __shfl_xor(acc, 2);
  acc += __shfl_xor(acc, 4);  acc += __shfl_xor(acc, 8);
  acc += __shfl_xor(acc, 16); acc += __shfl_xor(acc, 32);
  if (l == 0) out[b*OUTn + o] = sigmoidf_(acc + lin_b[o]);
}

extern "C" void kernel_launch(void* const* d_in, const int* in_sizes, int n_in,
                              void* d_out, int out_size, void* d_ws, size_t ws_size,
                              hipStream_t stream) {
  const float* x      = (const float*)d_in[0];
  const float* A      = (const float*)d_in[1];
  const float* w_z    = (const float*)d_in[2];
  const float* w_c    = (const float*)d_in[3];
  const float* u_z    = (const float*)d_in[4];
  const float* u_c    = (const float*)d_in[5];
  const float* b_z    = (const float*)d_in[6];
  const float* b_c    = (const float*)d_in[7];
  const float* u_node = (const float*)d_in[8];
  const float* u_msg  = (const float*)d_in[9];
  const float* lin_w  = (const float*)d_in[10];
  const float* lin_b  = (const float*)d_in[11];
  float* out = (float*)d_out;
  float* ws  = (float*)d_ws;

  const size_t SZ = (size_t)Bb*Nn*Nn*Ff;  // 1,048,576 floats
  float* wzxb = ws;
  float* wcxb = ws + SZ;
  float* mf0  = ws + 2*SZ;
  float* mf1  = ws + 3*SZ;
  float* enc  = ws + 4*SZ;

  // t=0 fused into precompute
  precompute_pair<<<NPAIR, 64, 0, stream>>>(x, w_z, w_c, b_z, b_c,
                                            wzxb, wcxb, mf0);

  const float* rd = mf0; float* wr = mf1;
  for (int t = 1; t < Tt; ++t) {
    edge_update<<<dim3(Bb, Nn, 2), 256, 0, stream>>>(A, u_z, u_c, wzxb, wcxb,
                                                     rd, wr);
    float* tmp = (float*)rd; rd = wr; wr = tmp;
  }
  finalize_enc<<<Bb*Nn, 64, 0, stream>>>(x, A, rd, u_node, u_msg, enc);
  linear_out<<<Bb*OUTn, 64, 0, stream>>>(enc, lin_w, lin_b, out);
}